// Round 6
// baseline (510.560 us; speedup 1.0000x reference)
//
#include <hip/hip_runtime.h>

// LocallyConnected3DFlipout:
//   out[b,p,f] = sum_k patch[b,p,k]*loc[p,k,f]
//              + sign_out[b,p,f]*sum_k (x*sign_in)patch[b,p,k]*(softplus(rho)*eps)[p,k,f]
//              + bias[f]
// patch k = c*27 + (kd*9+kh*3+kw)  (channel slowest, spatial row-major fastest).
//
// R6: async weight streaming via __builtin_amdgcn_global_load_lds.
// R2/R5 proved VGPR-held prefetch spills (WRITE 11 MB -> 0.6-1.4 GB). DMA
// direct-to-LDS holds nothing in registers. K split into 9 chunks of 12
// (chunk q = (kd,kh) row; tap = 3q+kw). Per chunk per array: 192 slots = 3
// full-wave DMA instrs; wave w<3 stages array w (own vmcnt drains own DMA at
// the barrier). Pipeline: issue DMA(q+2) -> raw[q&1], transform(q+1)
// raw->packed bf16 (softplus once per weight), compute(q) from packed[q&1],
// __syncthreads. DMA(q+2) is in flight across the whole compute span, so the
// barrier drain is HBM-productive. Compute mapping/epilogue = verified R3
// (absmax 0.0156 vs 0.0578 threshold with bf16 weights).

constexpr int Bn   = 32;
constexpr int Dn   = 30;
constexpr int Cn   = 4;
constexpr int ODn  = 28;
constexpr int Pn   = ODn * ODn * ODn;   // 21952
constexpr int Tt   = 27;
constexpr int Kn   = Tt * Cn;           // 108
constexpr int PPB  = 16;                // positions per block
constexpr int THREADS = 256;
constexpr int NCH  = 9;                 // chunks per tile
constexpr int CHK  = 12;                // items per p per chunk (4c x 3kw)
constexpr int SLOTS = PPB * CHK;        // 192 slots per array per chunk
constexpr int PST  = 13;                // packed row stride (uint4) per p

__device__ __forceinline__ unsigned bf16rne(float f) {
    unsigned u = __float_as_uint(f);
    return (u + 0x7fffu + ((u >> 16) & 1u)) >> 16;
}
__device__ __forceinline__ float bflo(unsigned u) { return __uint_as_float(u << 16); }
__device__ __forceinline__ float bfhi(unsigned u) { return __uint_as_float(u & 0xffff0000u); }

__device__ __forceinline__ uint4 packw(float4 L, float4 R, float4 E) {
    float nx = (R.x > 15.f ? R.x : __logf(1.f + __expf(R.x))) * E.x;
    float ny = (R.y > 15.f ? R.y : __logf(1.f + __expf(R.y))) * E.y;
    float nz = (R.z > 15.f ? R.z : __logf(1.f + __expf(R.z))) * E.z;
    float nw = (R.w > 15.f ? R.w : __logf(1.f + __expf(R.w))) * E.w;
    uint4 pk;
    pk.x = bf16rne(L.x) | (bf16rne(L.y) << 16);
    pk.y = bf16rne(L.z) | (bf16rne(L.w) << 16);
    pk.z = bf16rne(nx)  | (bf16rne(ny) << 16);
    pk.w = bf16rne(nz)  | (bf16rne(nw) << 16);
    return pk;
}

// Async global->LDS, 16 B per lane, lane i lands at ldsbase + i*16.
// AS casts via integer round-trip (CK idiom): AS3 ptrs are 32-bit, low 32
// bits of a generic LDS pointer are the LDS offset.
__device__ __forceinline__ void gld16(const float4* g, const float4* l) {
    __builtin_amdgcn_global_load_lds(
        (const __attribute__((address_space(1))) void*)(uintptr_t)(const void*)g,
        (__attribute__((address_space(3))) void*)(unsigned)(uintptr_t)(const void*)l,
        16, 0, 0);
}

__global__ __launch_bounds__(THREADS) void lc3d_flipout_kernel(
    const float* __restrict__ x,        // [B,30,30,30,4]
    const float* __restrict__ loc,      // [P,108,4]
    const float* __restrict__ rho,      // [P,108,4]
    const float* __restrict__ bias,     // [4]
    const float* __restrict__ eps,      // [P,108,4]
    const float* __restrict__ sgn_in,   // [B,30,30,30,4]
    const float* __restrict__ sgn_out,  // [B,P,4]
    float* __restrict__ out)            // [B,P,4]
{
    __shared__ float4 raw[2][3 * SLOTS];   // [buf][array*192 + slot], 18432 B
    __shared__ uint4  pck[2][PPB * PST];   // [buf][pl*13 + c*3 + kw], 6656 B

    const int tid    = threadIdx.x;
    const int lane   = tid & 63;
    const int wv     = tid >> 6;
    const int p_base = blockIdx.x * PPB;

    const float4* loc4 = (const float4*)loc;
    const float4* rho4 = (const float4*)rho;
    const float4* eps4 = (const float4*)eps;

    // ---- DMA addressing: slot s = k*64 + lane, s in [0,192).
    //      spl = s/12, r = s%12, c = r/3, j = r%3
    //      gidx(float4) = (p_base+spl)*108 + c*27 + 3q + j  (chunk q adds 3)
    int soff0, soff1, soff2;
    {
        int s = lane;               // k=0
        int spl = s / 12, r = s - spl * 12, c = r / 3, j = r - c * 3;
        soff0 = (p_base + spl) * Kn + c * Tt + j;
        s = 64 + lane;              // k=1
        spl = s / 12; r = s - spl * 12; c = r / 3; j = r - c * 3;
        soff1 = (p_base + spl) * Kn + c * Tt + j;
        s = 128 + lane;             // k=2
        spl = s / 12; r = s - spl * 12; c = r / 3; j = r - c * 3;
        soff2 = (p_base + spl) * Kn + c * Tt + j;
    }
    const float4* abase = (wv == 0) ? loc4 : (wv == 1) ? rho4 : eps4;

#define ISSUE(q, buf)                                                        \
    if (wv < 3) {                                                            \
        const float4* ab = abase + 3 * (q);                                  \
        gld16(ab + soff0, &raw[buf][wv * SLOTS + 0]);                        \
        gld16(ab + soff1, &raw[buf][wv * SLOTS + 64]);                       \
        gld16(ab + soff2, &raw[buf][wv * SLOTS + 128]);                      \
    }

#define TRANSFORM(rb, nb)                                                    \
    if (tid < SLOTS) {                                                       \
        const float4 L = raw[rb][0 * SLOTS + tid];                           \
        const float4 R = raw[rb][1 * SLOTS + tid];                           \
        const float4 E = raw[rb][2 * SLOTS + tid];                           \
        const int tpl = tid / 12, tr = tid - tpl * 12;                       \
        pck[nb][tpl * PST + tr] = packw(L, R, E);                            \
    }

    // ---- Compute-side mapping (R3, verified) ----
    const int pl = tid & 15;
    const int bh = tid >> 4;            // 0..15
    const int b0 = bh, b1 = bh + 16;
    const int p  = p_base + pl;
    const int od   = p / (ODn * ODn);
    const int prem = p - od * (ODn * ODn);
    const int oh   = prem / ODn;
    const int ow   = prem - oh * ODn;

    const float4* x4 = (const float4*)x;
    const float4* s4 = (const float4*)sgn_in;
    const size_t v0 = (((size_t)b0 * Dn + od) * Dn + oh) * Dn + ow;
    const size_t v1 = (((size_t)b1 * Dn + od) * Dn + oh) * Dn + ow;

    float a00=0.f,a01=0.f,a02=0.f,a03=0.f;   // mean acc, b0
    float a10=0.f,a11=0.f,a12=0.f,a13=0.f;   // mean acc, b1
    float n00=0.f,n01=0.f,n02=0.f,n03=0.f;   // noise acc, b0
    float n10=0.f,n11=0.f,n12=0.f,n13=0.f;   // noise acc, b1

#define CHAN(WV, xa_c, sa_c, xb_c, sb_c)                                     \
    {                                                                        \
        const float m0 = bflo(WV.x), m1 = bfhi(WV.x);                        \
        const float m2 = bflo(WV.y), m3 = bfhi(WV.y);                        \
        const float q0 = bflo(WV.z), q1 = bfhi(WV.z);                        \
        const float q2 = bflo(WV.w), q3 = bfhi(WV.w);                        \
        a00 = fmaf(xa_c, m0, a00); a01 = fmaf(xa_c, m1, a01);                \
        a02 = fmaf(xa_c, m2, a02); a03 = fmaf(xa_c, m3, a03);                \
        a10 = fmaf(xb_c, m0, a10); a11 = fmaf(xb_c, m1, a11);                \
        a12 = fmaf(xb_c, m2, a12); a13 = fmaf(xb_c, m3, a13);                \
        const float ya = (xa_c) * (sa_c);                                    \
        const float yb = (xb_c) * (sb_c);                                    \
        n00 = fmaf(ya, q0, n00); n01 = fmaf(ya, q1, n01);                    \
        n02 = fmaf(ya, q2, n02); n03 = fmaf(ya, q3, n03);                    \
        n10 = fmaf(yb, q0, n10); n11 = fmaf(yb, q1, n11);                    \
        n12 = fmaf(yb, q2, n12); n13 = fmaf(yb, q3, n13);                    \
    }

    // ---- Prologue: chunks 0,1 in flight; transform 0 ----
    ISSUE(0, 0);
    ISSUE(1, 1);
    __syncthreads();                 // drains DMA(0),DMA(1) (issuing waves)
    TRANSFORM(0, 0);
    __syncthreads();                 // publish packed[0]

    // ---- Pipeline: DMA(q+2) || transform(q+1) || compute(q) ----
    #pragma unroll
    for (int q = 0; q < NCH; ++q) {
        if (q + 2 < NCH) { ISSUE(q + 2, q & 1); }
        if (q + 1 < NCH) { TRANSFORM((q + 1) & 1, (q + 1) & 1); }

        const int kd = q / 3, kh = q - kd * 3;
        const uint4* wp = &pck[q & 1][pl * PST];
        #pragma unroll
        for (int kw = 0; kw < 3; ++kw) {
            const int roff = (kd * Dn + kh) * Dn + kw;
            const float4 xa = x4[v0 + roff];
            const float4 sa = s4[v0 + roff];
            const float4 xb = x4[v1 + roff];
            const float4 sb = s4[v1 + roff];
            const uint4 w0 = wp[0 * 3 + kw];
            const uint4 w1 = wp[1 * 3 + kw];
            const uint4 w2 = wp[2 * 3 + kw];
            const uint4 w3 = wp[3 * 3 + kw];
            CHAN(w0, xa.x, sa.x, xb.x, sb.x);
            CHAN(w1, xa.y, sa.y, xb.y, sb.y);
            CHAN(w2, xa.z, sa.z, xb.z, sb.z);
            CHAN(w3, xa.w, sa.w, xb.w, sb.w);
        }
        __syncthreads();             // publish packed[(q+1)&1]; drain DMA(q+2)
    }
#undef CHAN
#undef ISSUE
#undef TRANSFORM

    // ---- Epilogue: coalesced (16 consecutive p per cluster) ----
    const float4 bi = *(const float4*)bias;
    const size_t ob0 = (size_t)b0 * Pn + p;
    const size_t ob1 = (size_t)b1 * Pn + p;
    const float4 so0 = ((const float4*)sgn_out)[ob0];
    const float4 so1 = ((const float4*)sgn_out)[ob1];
    float4 o0, o1;
    o0.x = fmaf(so0.x, n00, a00) + bi.x;
    o0.y = fmaf(so0.y, n01, a01) + bi.y;
    o0.z = fmaf(so0.z, n02, a02) + bi.z;
    o0.w = fmaf(so0.w, n03, a03) + bi.w;
    o1.x = fmaf(so1.x, n10, a10) + bi.x;
    o1.y = fmaf(so1.y, n11, a11) + bi.y;
    o1.z = fmaf(so1.z, n12, a12) + bi.z;
    o1.w = fmaf(so1.w, n13, a13) + bi.w;
    ((float4*)out)[ob0] = o0;
    ((float4*)out)[ob1] = o1;
}

extern "C" void kernel_launch(void* const* d_in, const int* in_sizes, int n_in,
                              void* d_out, int out_size, void* d_ws, size_t ws_size,
                              hipStream_t stream) {
    const float* x    = (const float*)d_in[0];
    const float* loc  = (const float*)d_in[1];
    const float* rho  = (const float*)d_in[2];
    const float* bias = (const float*)d_in[3];
    const float* eps  = (const float*)d_in[4];
    const float* si   = (const float*)d_in[5];
    const float* so   = (const float*)d_in[6];
    float* out = (float*)d_out;

    lc3d_flipout_kernel<<<dim3(Pn / PPB), dim3(THREADS), 0, stream>>>(
        x, loc, rho, bias, eps, si, so, out);
}

// Round 7
// 203.825 us; speedup vs baseline: 2.5049x; 2.5049x over previous
//
#include <hip/hip_runtime.h>

// LocallyConnected3DFlipout:
//   out[b,p,f] = sum_k patch[b,p,k]*loc[p,k,f]
//              + sign_out[b,p,f]*sum_k (x*sign_in)patch[b,p,k]*(softplus(rho)*eps)[p,k,f]
//              + bias[f]
// patch k = c*27 + (kd*9+kh*3+kw)  (channel slowest, spatial row-major fastest).
//
// R7 = R3 (best verified: 98.6 us kernel, VGPR 92, zero spill) + two changes
// that do NOT touch the compute body:
//  1. XCD-contiguous tiles: assuming dispatch maps block i -> XCD i%8, give
//     each XCD a contiguous run of p-tiles so its concurrent x/sign_in
//     working set (~2-3 MB) fits the 4 MB per-XCD L2. In R3 the round-robin
//     mapping spread each XCD over ~13 MB -> x re-reads (607 MB logical)
//     came from L3 at 2-4x the latency; VALUBusy was stuck at 25%.
//  2. Persistent 2-tile blocks: grid = 1280 = exact residency (5 blocks/CU);
//     92 blocks run a second tile. Removes R3's 92-block straggler tail and
//     staggers stage/compute phases across blocks.
// R4 (two-kernel), R5 (VGPR prefetch), R6 (DMA pipeline) all regressed —
// spills or cross-XCD re-fetch. Lesson: keep the R3 body, fix locality/tail.

constexpr int Bn   = 32;
constexpr int Dn   = 30;
constexpr int Cn   = 4;
constexpr int ODn  = 28;
constexpr int Pn   = ODn * ODn * ODn;   // 21952
constexpr int Tt   = 27;
constexpr int Kn   = Tt * Cn;           // 108
constexpr int PPB  = 16;                // positions per tile
constexpr int NT   = Pn / PPB;          // 1372 tiles
constexpr int THREADS = 256;
constexpr int WSTRIDE = Kn + 1;         // 109 uint4/p (p-stride 436 dw == 20 mod 32 -> 2-way max, free)
constexpr int GRID = 1280;              // 5 blocks/CU x 256 CU

__device__ __forceinline__ unsigned bf16rne(float f) {
    unsigned u = __float_as_uint(f);
    return (u + 0x7fffu + ((u >> 16) & 1u)) >> 16;
}
__device__ __forceinline__ float bflo(unsigned u) { return __uint_as_float(u << 16); }
__device__ __forceinline__ float bfhi(unsigned u) { return __uint_as_float(u & 0xffff0000u); }

__global__ __launch_bounds__(THREADS) void lc3d_flipout_kernel(
    const float* __restrict__ x,        // [B,30,30,30,4]
    const float* __restrict__ loc,      // [P,108,4]
    const float* __restrict__ rho,      // [P,108,4]
    const float* __restrict__ bias,     // [4]
    const float* __restrict__ eps,      // [P,108,4]
    const float* __restrict__ sgn_in,   // [B,30,30,30,4]
    const float* __restrict__ sgn_out,  // [B,P,4]
    float* __restrict__ out)            // [B,P,4]
{
    __shared__ uint4 wsh[PPB * WSTRIDE];

    const int tid = threadIdx.x;

    // ---- XCD-contiguous persistent tile assignment ----
    // 1372 tiles over 8 XCDs: first 4 XCDs own 172, last 4 own 171.
    // Block i -> xcd i&7, slot i>>3 (160 slots/xcd). Slot s covers tile
    // Tx+s and (if s+160 < Nx) tile Tx+s+160.  48 + 44 = 92 double blocks.
    const int xcd  = blockIdx.x & 7;
    const int slot = blockIdx.x >> 3;
    const int Nx = (xcd < 4) ? 172 : 171;
    const int Tx = (xcd < 4) ? xcd * 172 : 688 + (xcd - 4) * 171;
    const int ntiles = (slot + 160 < Nx) ? 2 : 1;

    for (int it = 0; it < ntiles; ++it) {
        const int p_base = (Tx + slot + it * 160) * PPB;
        if (it) __syncthreads();        // LDS slab reuse hazard between tiles

        // ---- Stage weights: 1728 uint4; coalesced global, sequential LDS ----
        const float4* loc4 = (const float4*)loc + (size_t)p_base * Kn;
        const float4* rho4 = (const float4*)rho + (size_t)p_base * Kn;
        const float4* eps4 = (const float4*)eps + (size_t)p_base * Kn;
        for (int g = tid; g < PPB * Kn; g += THREADS) {
            const int plc = g / Kn;
            const int k   = g - plc * Kn;
            const float4 L = loc4[g];
            const float4 R = rho4[g];
            const float4 E = eps4[g];
            float nx = (R.x > 15.f ? R.x : __logf(1.f + __expf(R.x))) * E.x;
            float ny = (R.y > 15.f ? R.y : __logf(1.f + __expf(R.y))) * E.y;
            float nz = (R.z > 15.f ? R.z : __logf(1.f + __expf(R.z))) * E.z;
            float nw = (R.w > 15.f ? R.w : __logf(1.f + __expf(R.w))) * E.w;
            uint4 pk;
            pk.x = bf16rne(L.x) | (bf16rne(L.y) << 16);
            pk.y = bf16rne(L.z) | (bf16rne(L.w) << 16);
            pk.z = bf16rne(nx)  | (bf16rne(ny) << 16);
            pk.w = bf16rne(nz)  | (bf16rne(nw) << 16);
            wsh[plc * WSTRIDE + k] = pk;
        }
        __syncthreads();

        // ---- Compute (verified R3 body): lane = (bh, pl), 2 batches/thread ----
        const int pl = tid & 15;
        const int bh = tid >> 4;
        const int b0 = bh, b1 = bh + 16;
        const int p  = p_base + pl;
        const int od = p / (ODn * ODn);
        const int prem = p - od * (ODn * ODn);
        const int oh = prem / ODn;
        const int ow = prem - oh * ODn;
        const float4* x4 = (const float4*)x;
        const float4* s4 = (const float4*)sgn_in;
        const size_t v0 = (((size_t)b0 * Dn + od) * Dn + oh) * Dn + ow;
        const size_t v1 = (((size_t)b1 * Dn + od) * Dn + oh) * Dn + ow;
        const uint4* wp = wsh + pl * WSTRIDE;

        float a00=0.f,a01=0.f,a02=0.f,a03=0.f, a10=0.f,a11=0.f,a12=0.f,a13=0.f;
        float n00=0.f,n01=0.f,n02=0.f,n03=0.f, n10=0.f,n11=0.f,n12=0.f,n13=0.f;

#define CHAN(c, xa_c, sa_c, xb_c, sb_c)                                      \
        {                                                                    \
            const uint4 wv = wp[(c) * Tt + t];                               \
            const float m0 = bflo(wv.x), m1 = bfhi(wv.x);                    \
            const float m2 = bflo(wv.y), m3 = bfhi(wv.y);                    \
            const float q0 = bflo(wv.z), q1 = bfhi(wv.z);                    \
            const float q2 = bflo(wv.w), q3 = bfhi(wv.w);                    \
            a00 = fmaf(xa_c, m0, a00); a01 = fmaf(xa_c, m1, a01);            \
            a02 = fmaf(xa_c, m2, a02); a03 = fmaf(xa_c, m3, a03);            \
            a10 = fmaf(xb_c, m0, a10); a11 = fmaf(xb_c, m1, a11);            \
            a12 = fmaf(xb_c, m2, a12); a13 = fmaf(xb_c, m3, a13);            \
            const float ya = (xa_c) * (sa_c);                                \
            const float yb = (xb_c) * (sb_c);                                \
            n00 = fmaf(ya, q0, n00); n01 = fmaf(ya, q1, n01);                \
            n02 = fmaf(ya, q2, n02); n03 = fmaf(ya, q3, n03);                \
            n10 = fmaf(yb, q0, n10); n11 = fmaf(yb, q1, n11);                \
            n12 = fmaf(yb, q2, n12); n13 = fmaf(yb, q3, n13);                \
        }

        #pragma unroll
        for (int kd = 0; kd < 3; ++kd) {
            #pragma unroll
            for (int kh = 0; kh < 3; ++kh) {
                const int roff = (kd * Dn + kh) * Dn;
                #pragma unroll
                for (int kw = 0; kw < 3; ++kw) {
                    const int t = (kd * 3 + kh) * 3 + kw;
                    const float4 xa = x4[v0 + roff + kw];
                    const float4 sa = s4[v0 + roff + kw];
                    const float4 xb = x4[v1 + roff + kw];
                    const float4 sb = s4[v1 + roff + kw];
                    CHAN(0, xa.x, sa.x, xb.x, sb.x);
                    CHAN(1, xa.y, sa.y, xb.y, sb.y);
                    CHAN(2, xa.z, sa.z, xb.z, sb.z);
                    CHAN(3, xa.w, sa.w, xb.w, sb.w);
                }
            }
        }
#undef CHAN

        // ---- Epilogue: coalesced (16 consecutive p per cluster) ----
        const float4 bi = *(const float4*)bias;
        const size_t ob0 = (size_t)b0 * Pn + p;
        const size_t ob1 = (size_t)b1 * Pn + p;
        const float4 so0 = ((const float4*)sgn_out)[ob0];
        const float4 so1 = ((const float4*)sgn_out)[ob1];
        float4 o0, o1;
        o0.x = fmaf(so0.x, n00, a00) + bi.x;
        o0.y = fmaf(so0.y, n01, a01) + bi.y;
        o0.z = fmaf(so0.z, n02, a02) + bi.z;
        o0.w = fmaf(so0.w, n03, a03) + bi.w;
        o1.x = fmaf(so1.x, n10, a10) + bi.x;
        o1.y = fmaf(so1.y, n11, a11) + bi.y;
        o1.z = fmaf(so1.z, n12, a12) + bi.z;
        o1.w = fmaf(so1.w, n13, a13) + bi.w;
        ((float4*)out)[ob0] = o0;
        ((float4*)out)[ob1] = o1;
    }
}

extern "C" void kernel_launch(void* const* d_in, const int* in_sizes, int n_in,
                              void* d_out, int out_size, void* d_ws, size_t ws_size,
                              hipStream_t stream) {
    const float* x    = (const float*)d_in[0];
    const float* loc  = (const float*)d_in[1];
    const float* rho  = (const float*)d_in[2];
    const float* bias = (const float*)d_in[3];
    const float* eps  = (const float*)d_in[4];
    const float* si   = (const float*)d_in[5];
    const float* so   = (const float*)d_in[6];
    float* out = (float*)d_out;

    lc3d_flipout_kernel<<<dim3(GRID), dim3(THREADS), 0, stream>>>(
        x, loc, rho, bias, eps, si, so, out);
}